// Round 6
// baseline (54.008 us; speedup 1.0000x reference)
//
#include <hip/hip_runtime.h>

#define W_LEN 4
#define OUT_C 3
#define KK    3
#define HH    16
#define FC_HID 6
#define W_NEW 2          // W_LEN - K + 1
#define FC_IN 96         // OUT_C * W_NEW * HH
#define TT    16384
#define BB    32

// ws layout (floats):
//   [0..575]   W1s[j*96+i]  = -4*log2e * fc_hid_w[j*96+i]
//   [576..581] B1s[j]       =  2*log2e * (fc_hid_b[j] + sum_i fc_hid_w[j*96+i])
//   [582..608] CWs[27]      =  2*log2e * conv_w
//   [609..611] CBs[3]       =  2*log2e * conv_b
//   [612..623] W2s[k*6+j]   = -2 * fc_out_w[k*6+j]
//   [624..625] B2s[k]       =  fc_out_b[k] + sum_j fc_out_w[k*6+j]
#define WS_W1 0
#define WS_B1 576
#define WS_CW 582
#define WS_CB 609
#define WS_W2 612
#define WS_B2 624

#define TWO_LOG2E 2.8853900817779268f

__global__ __launch_bounds__(128) void rvtdcnn_preproc(
    const float* __restrict__ conv_w, const float* __restrict__ conv_b,
    const float* __restrict__ fc_hid_w, const float* __restrict__ fc_hid_b,
    const float* __restrict__ fc_out_w, const float* __restrict__ fc_out_b,
    float* __restrict__ ws)
{
    __shared__ float raw[FC_HID][FC_IN];
    const int tid = threadIdx.x;
    if (tid < FC_IN) {
        #pragma unroll
        for (int j = 0; j < FC_HID; ++j) {
            float w = fc_hid_w[j * FC_IN + tid];
            raw[j][tid] = w;
            ws[WS_W1 + j * FC_IN + tid] = -2.0f * TWO_LOG2E * w;
        }
    } else if (tid < FC_IN + 27) {
        const int i = tid - FC_IN;
        ws[WS_CW + i] = TWO_LOG2E * conv_w[i];
    } else if (tid < FC_IN + 30) {
        const int i = tid - FC_IN - 27;
        ws[WS_CB + i] = TWO_LOG2E * conv_b[i];
    }
    __syncthreads();
    if (tid < FC_HID) {
        float s = fc_hid_b[tid];
        #pragma unroll 8
        for (int i = 0; i < FC_IN; ++i) s += raw[tid][i];
        ws[WS_B1 + tid] = TWO_LOG2E * s;
    } else if (tid >= 8 && tid < 8 + 2) {
        const int k = tid - 8;
        float s = fc_out_b[k];
        #pragma unroll
        for (int j = 0; j < FC_HID; ++j) {
            float w = fc_out_w[k * FC_HID + j];
            s += w;
            ws[WS_W2 + k * FC_HID + j] = -2.0f * w;
        }
        ws[WS_B2 + k] = s;
    }
}

// sigmoid-ish core: r = rcp(exp2(a') + 1), where a' already includes 2*log2e.
// tanh(a) = 1 - 2r; the affine parts are prefolded into ws weights.
__device__ __forceinline__ float rcore(float ap) {
    float e = __builtin_amdgcn_exp2f(ap);
    return __builtin_amdgcn_rcpf(e + 1.0f);
}

// Round-4 structure (fully unrolled, 4 sliding row slots, no spill) with all
// tanh affine work prefolded into ws (preproc kernel above).
__global__ __launch_bounds__(256, 2)
void rvtdcnn_fused6(
    const float* __restrict__ x,
    const float* __restrict__ ws,
    float* __restrict__ out)
{
    const int gid = blockIdx.x * blockDim.x + threadIdx.x;   // [0, B*T/2)
    const int b  = gid >> 13;            // / (TT/2)
    const int t0 = (gid & 8191) << 1;    // even position

    const float4* x4 = reinterpret_cast<const float4*>(x) + (size_t)(b * TT + t0) * (HH / 4);

#define LOAD_ROW(R, OFF)                                                     \
    do {                                                                     \
        if (t0 + (OFF) < 0) {                                                \
            _Pragma("unroll") for (int c = 0; c < HH; ++c) R[c] = 0.0f;      \
        } else {                                                             \
            _Pragma("unroll") for (int q = 0; q < HH / 4; ++q) {             \
                float4 v = x4[(OFF) * (HH / 4) + q];                         \
                R[q * 4 + 0] = v.x; R[q * 4 + 1] = v.y;                      \
                R[q * 4 + 2] = v.z; R[q * 4 + 3] = v.w;                      \
            }                                                                \
        }                                                                    \
    } while (0)

    // ---- prescaled conv weights (wave-uniform -> scalar regs) ----
    float cw[OUT_C][KK][KK];
    #pragma unroll
    for (int oc = 0; oc < OUT_C; ++oc)
        #pragma unroll
        for (int kr = 0; kr < KK; ++kr)
            #pragma unroll
            for (int kc = 0; kc < KK; ++kc)
                cw[oc][kr][kc] = ws[WS_CW + (oc * KK + kr) * KK + kc];
    float cb[OUT_C];
    #pragma unroll
    for (int oc = 0; oc < OUT_C; ++oc) cb[oc] = ws[WS_CB + oc];

    // h' accumulators (pre-scaled by 2log2e; start from folded bias)
    float h_a[FC_HID], h_b[FC_HID];
    #pragma unroll
    for (int j = 0; j < FC_HID; ++j) {
        const float bj = ws[WS_B1 + j];
        h_a[j] = bj;
        h_b[j] = bj;
    }
    const float* W1 = ws + WS_W1;

#define CONV_ROW(RA, RB, RC, DO_A, IA, DO_B, IB)                             \
    _Pragma("unroll") for (int oc = 0; oc < OUT_C; ++oc) {                   \
        _Pragma("unroll") for (int c = 0; c < HH; ++c) {                     \
            float acc = cb[oc];                                              \
            _Pragma("unroll") for (int kc = 0; kc < KK; ++kc) {              \
                const int cc = c + kc - 1;                                   \
                if (cc >= 0 && cc < HH) {                                    \
                    acc = fmaf(RA[cc], cw[oc][0][kc], acc);                  \
                    acc = fmaf(RB[cc], cw[oc][1][kc], acc);                  \
                    acc = fmaf(RC[cc], cw[oc][2][kc], acc);                  \
                }                                                            \
            }                                                                \
            const float r = rcore(acc);  /* feature = 1-2r, folded into W1 */\
            if (DO_A) {                                                      \
                const int ia = (oc * W_NEW + (IA)) * HH + c;                 \
                _Pragma("unroll") for (int j = 0; j < FC_HID; ++j)           \
                    h_a[j] = fmaf(r, W1[j * FC_IN + ia], h_a[j]);            \
            }                                                                \
            if (DO_B) {                                                      \
                const int ib = (oc * W_NEW + (IB)) * HH + c;                 \
                _Pragma("unroll") for (int j = 0; j < FC_HID; ++j)           \
                    h_b[j] = fmaf(r, W1[j * FC_IN + ib], h_b[j]);            \
            }                                                                \
        }                                                                    \
    }

    float rA[HH], rB[HH], rC[HH], rD[HH];
    LOAD_ROW(rA, -3);
    LOAD_ROW(rB, -2);
    LOAD_ROW(rC, -1);
    LOAD_ROW(rD,  0);

    // crow0: rows (t0-3..t0-1) -> pos t0 wr=0; rA (t0-3) dies here
    CONV_ROW(rA, rB, rC, true, 0, false, 0);
    LOAD_ROW(rA, 1);                       // slot reuse: rA <- row t0+1
    // crow1: rows (t0-2..t0)   -> pos t0 wr=1, pos t0+1 wr=0
    CONV_ROW(rB, rC, rD, true, 1, true, 0);
    // crow2: rows (t0-1..t0+1) -> pos t0+1 wr=1
    CONV_ROW(rC, rD, rA, false, 0, true, 1);

    // ---- FC1 "tanh" (as rho) -> FC2 with folded weights ----
    float ya0 = ws[WS_B2 + 0], ya1 = ws[WS_B2 + 1];
    float yb0 = ya0, yb1 = ya1;
    #pragma unroll
    for (int j = 0; j < FC_HID; ++j) {
        const float w0 = ws[WS_W2 + j];           // k=0
        const float w1 = ws[WS_W2 + FC_HID + j];  // k=1
        const float ra = rcore(h_a[j]);
        const float rb = rcore(h_b[j]);
        ya0 = fmaf(ra, w0, ya0);
        ya1 = fmaf(ra, w1, ya1);
        yb0 = fmaf(rb, w0, yb0);
        yb1 = fmaf(rb, w1, yb1);
    }

    float4 o;
    o.x = ya0; o.y = ya1; o.z = yb0; o.w = yb1;
    reinterpret_cast<float4*>(out)[(b * TT + t0) >> 1] = o;

#undef LOAD_ROW
#undef CONV_ROW
}

extern "C" void kernel_launch(void* const* d_in, const int* in_sizes, int n_in,
                              void* d_out, int out_size, void* d_ws, size_t ws_size,
                              hipStream_t stream) {
    const float* x        = (const float*)d_in[0];
    const float* conv_w   = (const float*)d_in[1];
    const float* conv_b   = (const float*)d_in[2];
    const float* fc_hid_w = (const float*)d_in[3];
    const float* fc_hid_b = (const float*)d_in[4];
    const float* fc_out_w = (const float*)d_in[5];
    const float* fc_out_b = (const float*)d_in[6];
    float* out = (float*)d_out;
    float* ws  = (float*)d_ws;

    rvtdcnn_preproc<<<1, 128, 0, stream>>>(conv_w, conv_b, fc_hid_w, fc_hid_b,
                                           fc_out_w, fc_out_b, ws);

    const int n_pairs = BB * TT / 2;       // 262144 threads
    const int block = 256;
    const int grid = n_pairs / block;      // 1024 blocks = 4 blocks/CU, uniform
    rvtdcnn_fused6<<<grid, block, 0, stream>>>(x, ws, out);
}

// Round 7
// 34.489 us; speedup vs baseline: 1.5660x; 1.5660x over previous
//
#include <hip/hip_runtime.h>

#define W_LEN 4
#define OUT_C 3
#define KK    3
#define HH    16
#define FC_HID 6
#define W_NEW 2          // W_LEN - K + 1
#define FC_IN 96         // OUT_C * W_NEW * HH
#define TT    16384
#define BB    32

__device__ __forceinline__ float tanh_fast(float x) {
    // tanh(x) = 1 - 2/(2^(x*2*log2e)+1): mul, exp2, add, rcp, fma
    float e = __builtin_amdgcn_exp2f(x * 2.8853900817779268f);
    float r = __builtin_amdgcn_rcpf(e + 1.0f);
    return fmaf(-2.0f, r, 1.0f);
}

// ONE position per thread (C=1) to double TLP: 2048 blocks = 8 blocks/CU.
// 3-slot sliding row window keeps live set ~64 VGPR so all 8 waves/SIMD fit.
// Weight path identical to the 33us fused4: direct kernel-arg s_loads.
__global__ __launch_bounds__(256, 2)
void rvtdcnn_fused7(
    const float* __restrict__ x,
    const float* __restrict__ conv_w,
    const float* __restrict__ conv_b,
    const float* __restrict__ fc_hid_w,
    const float* __restrict__ fc_hid_b,
    const float* __restrict__ fc_out_w,
    const float* __restrict__ fc_out_b,
    float* __restrict__ out)
{
    const int gid = blockIdx.x * blockDim.x + threadIdx.x;   // [0, B*T)
    const int b = gid >> 14;          // / TT
    const int t = gid & (TT - 1);     // % TT

    const float4* x4 = reinterpret_cast<const float4*>(x) + (size_t)(b * TT + t) * (HH / 4);

#define LOAD_ROW(R, OFF)                                                     \
    do {                                                                     \
        if (t + (OFF) < 0) {                                                 \
            _Pragma("unroll") for (int c = 0; c < HH; ++c) R[c] = 0.0f;      \
        } else {                                                             \
            _Pragma("unroll") for (int q = 0; q < HH / 4; ++q) {             \
                float4 v = x4[(OFF) * (HH / 4) + q];                         \
                R[q * 4 + 0] = v.x; R[q * 4 + 1] = v.y;                      \
                R[q * 4 + 2] = v.z; R[q * 4 + 3] = v.w;                      \
            }                                                                \
        }                                                                    \
    } while (0)

    float h[FC_HID];
    #pragma unroll
    for (int j = 0; j < FC_HID; ++j) h[j] = fc_hid_b[j];

    // Conv row over named slots RA,RB,RC (kr=0,1,2), scatter into h at wr=WR.
    // conv/FC1 weights indexed with compile-time offsets off kernel args:
    // wave-uniform -> s_load; compiler keeps them in SGPRs as it sees fit.
#define CONV_ROW(RA, RB, RC, WR)                                             \
    _Pragma("unroll") for (int oc = 0; oc < OUT_C; ++oc) {                   \
        _Pragma("unroll") for (int c = 0; c < HH; ++c) {                     \
            float acc = conv_b[oc];                                          \
            _Pragma("unroll") for (int kc = 0; kc < KK; ++kc) {              \
                const int cc = c + kc - 1;                                   \
                if (cc >= 0 && cc < HH) {                                    \
                    acc = fmaf(RA[cc], conv_w[(oc * KK + 0) * KK + kc], acc);\
                    acc = fmaf(RB[cc], conv_w[(oc * KK + 1) * KK + kc], acc);\
                    acc = fmaf(RC[cc], conv_w[(oc * KK + 2) * KK + kc], acc);\
                }                                                            \
            }                                                                \
            const float f = tanh_fast(acc);                                  \
            const int ia = (oc * W_NEW + (WR)) * HH + c;                     \
            _Pragma("unroll") for (int j = 0; j < FC_HID; ++j)               \
                h[j] = fmaf(f, fc_hid_w[j * FC_IN + ia], h[j]);              \
        }                                                                    \
    }

    float sA[HH], sB[HH], sC[HH];
    LOAD_ROW(sA, -3);
    LOAD_ROW(sB, -2);
    LOAD_ROW(sC, -1);

    // crow0: rows (t-3..t-1) -> wr=0; sA (t-3) dies here
    CONV_ROW(sA, sB, sC, 0);
    LOAD_ROW(sA, 0);                      // slot reuse: sA <- row t
    // crow1: rows (t-2..t)   -> wr=1
    CONV_ROW(sB, sC, sA, 1);

    // ---- FC1 tanh -> FC2 ----
    float y0 = fc_out_b[0];
    float y1 = fc_out_b[1];
    #pragma unroll
    for (int j = 0; j < FC_HID; ++j) {
        const float hj = tanh_fast(h[j]);
        y0 = fmaf(hj, fc_out_w[j], y0);
        y1 = fmaf(hj, fc_out_w[FC_HID + j], y1);
    }

    reinterpret_cast<float2*>(out)[gid] = make_float2(y0, y1);

#undef LOAD_ROW
#undef CONV_ROW
}

extern "C" void kernel_launch(void* const* d_in, const int* in_sizes, int n_in,
                              void* d_out, int out_size, void* d_ws, size_t ws_size,
                              hipStream_t stream) {
    const float* x        = (const float*)d_in[0];
    const float* conv_w   = (const float*)d_in[1];
    const float* conv_b   = (const float*)d_in[2];
    const float* fc_hid_w = (const float*)d_in[3];
    const float* fc_hid_b = (const float*)d_in[4];
    const float* fc_out_w = (const float*)d_in[5];
    const float* fc_out_b = (const float*)d_in[6];
    float* out = (float*)d_out;

    const int n = BB * TT;                 // 524288 threads, one per position
    const int block = 256;
    const int grid = n / block;            // 2048 blocks = 8 blocks/CU target
    rvtdcnn_fused7<<<grid, block, 0, stream>>>(x, conv_w, conv_b, fc_hid_w, fc_hid_b,
                                               fc_out_w, fc_out_b, out);
}

// Round 8
// 31.563 us; speedup vs baseline: 1.7111x; 1.0927x over previous
//
#include <hip/hip_runtime.h>

#define TT 16384
#define BB 32

typedef __attribute__((ext_vector_type(8))) short bf16x8;
typedef __attribute__((ext_vector_type(4))) float f32x4;

#define S1 2.8853900817779268f   // 2*log2(e)

__device__ __forceinline__ unsigned short f2bf(float v) {
    unsigned int u = __float_as_uint(v);
    u = (u + 0x7fffu + ((u >> 16) & 1u)) >> 16;   // RNE
    return (unsigned short)u;
}
__device__ __forceinline__ float rcore(float v) {   // r = 1/(exp2(v)+1); tanh = 1-2r folded downstream
    return __builtin_amdgcn_rcpf(__builtin_amdgcn_exp2f(v) + 1.0f);
}

// ---------------- preproc: build bf16 MFMA A-fragments + folded scalars in ws ----------------
// ws (uint view): frag f in [0,9): uints [f*256 + l*4, +4) = lane l's 8 bf16 (e ascending).
//   f=mt*2+kt   : A1 conv matrix  A1[m=c][k=r*16+h] = S1*conv_w[oc=mt][r][h-c+1] (|h-c|<=1, else 0)
//   f=6+kt2     : A2 fc1 matrix   A2[j][q] = -2*S1*fc_hid_w[j][(oc*2+wr)*16+c], q=(wr?48:0)+oc*16+c
// float view offset 2304: [0..2]=S1*conv_b, [3..8]=B1S[j]=S1*(b1+sum W1), [9..20]=W2S[k][j]=-2*w2,
//                         [21..22]=B2S[k]=b2+sum w2
__global__ __launch_bounds__(64) void rvt_prep(
    const float* __restrict__ conv_w, const float* __restrict__ conv_b,
    const float* __restrict__ fc_hid_w, const float* __restrict__ fc_hid_b,
    const float* __restrict__ fc_out_w, const float* __restrict__ fc_out_b,
    unsigned int* __restrict__ wsu)
{
    const int l = threadIdx.x;
    const int m = l & 15, g = l >> 4;

    for (int mt = 0; mt < 3; ++mt)
        for (int kt = 0; kt < 2; ++kt) {
            unsigned short hs[8];
            for (int e = 0; e < 8; ++e) {
                int k = kt * 32 + g * 8 + e;
                int r = k >> 4, hh = k & 15;
                int kc = hh - m + 1;
                float v = 0.f;
                if (r < 3 && kc >= 0 && kc <= 2) v = S1 * conv_w[(mt * 3 + r) * 3 + kc];
                hs[e] = f2bf(v);
            }
            int base = (mt * 2 + kt) * 256 + l * 4;
            wsu[base + 0] = hs[0] | ((unsigned)hs[1] << 16);
            wsu[base + 1] = hs[2] | ((unsigned)hs[3] << 16);
            wsu[base + 2] = hs[4] | ((unsigned)hs[5] << 16);
            wsu[base + 3] = hs[6] | ((unsigned)hs[7] << 16);
        }
    for (int kt = 0; kt < 3; ++kt) {
        unsigned short hs[8];
        for (int e = 0; e < 8; ++e) {
            int q = kt * 32 + g * 8 + e;
            float v = 0.f;
            if (m < 6 && q < 96) {
                int wr = (q >= 48) ? 1 : 0;
                int col = q - 48 * wr;
                int oc = col >> 4, c = col & 15;
                v = -2.f * S1 * fc_hid_w[m * 96 + (oc * 2 + wr) * 16 + c];
            }
            hs[e] = f2bf(v);
        }
        int base = (6 + kt) * 256 + l * 4;
        wsu[base + 0] = hs[0] | ((unsigned)hs[1] << 16);
        wsu[base + 1] = hs[2] | ((unsigned)hs[3] << 16);
        wsu[base + 2] = hs[4] | ((unsigned)hs[5] << 16);
        wsu[base + 3] = hs[6] | ((unsigned)hs[7] << 16);
    }
    float* wsS = (float*)(wsu + 2304);
    if (l < 3) wsS[l] = S1 * conv_b[l];
    if (l < 6) {
        float s = fc_hid_b[l];
        for (int i = 0; i < 96; ++i) s += fc_hid_w[l * 96 + i];
        wsS[3 + l] = S1 * s;
    }
    if (l < 2) {
        float s = fc_out_b[l];
        for (int j = 0; j < 6; ++j) {
            float w = fc_out_w[l * 6 + j];
            s += w;
            wsS[9 + l * 6 + j] = -2.f * w;
        }
        wsS[21 + l] = s;
    }
}

// ---------------- fused MFMA kernel: 64 positions per wave, no barriers ----------------
__device__ __forceinline__ void stage_row(char* S, const float* __restrict__ x,
                                          int b, int tb, int i) {
    const int trow = tb - 3 + i;
    uint4 w0 = {0u, 0u, 0u, 0u}, w1 = {0u, 0u, 0u, 0u};
    if (trow >= 0 && trow < TT) {
        const float4* p = (const float4*)x + (size_t)(b * TT + trow) * 4;
        float4 f0 = p[0], f1 = p[1], f2 = p[2], f3 = p[3];
        w0.x = f2bf(f0.x) | ((unsigned)f2bf(f0.y) << 16);
        w0.y = f2bf(f0.z) | ((unsigned)f2bf(f0.w) << 16);
        w0.z = f2bf(f1.x) | ((unsigned)f2bf(f1.y) << 16);
        w0.w = f2bf(f1.z) | ((unsigned)f2bf(f1.w) << 16);
        w1.x = f2bf(f2.x) | ((unsigned)f2bf(f2.y) << 16);
        w1.y = f2bf(f2.z) | ((unsigned)f2bf(f2.w) << 16);
        w1.z = f2bf(f3.x) | ((unsigned)f2bf(f3.y) << 16);
        w1.w = f2bf(f3.z) | ((unsigned)f2bf(f3.w) << 16);
    }
    uint4* d = (uint4*)(S + i * 32);
    d[0] = w0;
    d[1] = w1;
}

#define MFMA16(a, bb, cc) __builtin_amdgcn_mfma_f32_16x16x32_bf16((a), (bb), (cc), 0, 0, 0)

__global__ __launch_bounds__(256, 2) void rvt_mfma(
    const float* __restrict__ x, const uint4* __restrict__ wsA,
    const float* __restrict__ wsS, float* __restrict__ out)
{
    // per-wave LDS: staging 68 rows * 32B = 2176B; G 65 cols * 96B = 6240B
    __shared__ __align__(16) char smem[4 * 2176 + 4 * 6240];
    const int tid = threadIdx.x, wv = tid >> 6, l = tid & 63;
    const int n = l & 15, g = l >> 4;
    const int P0 = blockIdx.x << 8;           // 256 positions per block
    const int b  = P0 >> 14;                  // / TT
    const int tb = (P0 & (TT - 1)) + (wv << 6);

    char* S = smem + wv * 2176;
    char* G = smem + 4 * 2176 + wv * 6240;

    // ---- stage x rows tb-3 .. tb+63 (67 rows) as bf16 ----
    stage_row(S, x, b, tb, l);
    if (l < 3) stage_row(S, x, b, tb, l + 64);

    // ---- A fragments (held in VGPRs for the whole kernel) ----
    union { uint4 u; bf16x8 f; } cv;
    bf16x8 A1[6], A2[3];
    #pragma unroll
    for (int i = 0; i < 6; ++i) { cv.u = wsA[i * 64 + l]; A1[i] = cv.f; }
    #pragma unroll
    for (int i = 0; i < 3; ++i) { cv.u = wsA[(6 + i) * 64 + l]; A2[i] = cv.f; }

    const float cbs0 = wsS[0], cbs1 = wsS[1], cbs2 = wsS[2];
    // FC1 accumulator init for this lane's rows (rows j = g*4+reg; j>=6 -> 0)
    const int r0 = g * 4;
    const float b1i0 = (r0 + 0 < 6) ? wsS[3 + r0 + 0] : 0.f;
    const float b1i1 = (r0 + 1 < 6) ? wsS[3 + r0 + 1] : 0.f;
    const float b1i2 = (r0 + 2 < 6) ? wsS[3 + r0 + 2] : 0.f;
    const float b1i3 = (r0 + 3 < 6) ? wsS[3 + r0 + 3] : 0.f;
    const float w200 = wsS[9],  w201 = wsS[10], w202 = wsS[11];
    const float w203 = wsS[12], w204 = wsS[13], w205 = wsS[14];
    const float w210 = wsS[15], w211 = wsS[16], w212 = wsS[17];
    const float w213 = wsS[18], w214 = wsS[19], w215 = wsS[20];
    const float b2s0 = wsS[21], b2s1 = wsS[22];

    #pragma unroll
    for (int p = 0; p <= 4; ++p) {
        // ===== MFMA1: G-columns 16p..16p+15 (t' = tb-1+16p+n) =====
        // B[k][n]: k=(g*8+e) within ktile; window row r = k/16, h = k%15.. -> one b128/lane/ktile
        bf16x8 bk0 = *(const bf16x8*)(S + (16 * p + n + (g >> 1)) * 32 + (g & 1) * 16);
        bf16x8 bk1 = {0, 0, 0, 0, 0, 0, 0, 0};
        if (g < 2) bk1 = *(const bf16x8*)(S + (16 * p + n + 2) * 32 + (g & 1) * 16);

        f32x4 ac0 = {cbs0, cbs0, cbs0, cbs0};
        f32x4 ac1 = {cbs1, cbs1, cbs1, cbs1};
        f32x4 ac2 = {cbs2, cbs2, cbs2, cbs2};
        ac0 = MFMA16(A1[0], bk0, ac0); ac0 = MFMA16(A1[1], bk1, ac0);
        ac1 = MFMA16(A1[2], bk0, ac1); ac1 = MFMA16(A1[3], bk1, ac1);
        ac2 = MFMA16(A1[4], bk0, ac2); ac2 = MFMA16(A1[5], bk1, ac2);

        if (p < 4 || n == 0) {          // p=4 computes only the 65th column (n==0)
            const int colb = (16 * p + n) * 96 + g * 8;
            {
                float q0 = rcore(ac0.x), q1 = rcore(ac0.y), q2 = rcore(ac0.z), q3 = rcore(ac0.w);
                uint2 w; w.x = f2bf(q0) | ((unsigned)f2bf(q1) << 16);
                w.y = f2bf(q2) | ((unsigned)f2bf(q3) << 16);
                *(uint2*)(G + colb + 0)  = w;
            }
            {
                float q0 = rcore(ac1.x), q1 = rcore(ac1.y), q2 = rcore(ac1.z), q3 = rcore(ac1.w);
                uint2 w; w.x = f2bf(q0) | ((unsigned)f2bf(q1) << 16);
                w.y = f2bf(q2) | ((unsigned)f2bf(q3) << 16);
                *(uint2*)(G + colb + 32) = w;
            }
            {
                float q0 = rcore(ac2.x), q1 = rcore(ac2.y), q2 = rcore(ac2.z), q3 = rcore(ac2.w);
                uint2 w; w.x = f2bf(q0) | ((unsigned)f2bf(q1) << 16);
                w.y = f2bf(q2) | ((unsigned)f2bf(q3) << 16);
                *(uint2*)(G + colb + 64) = w;
            }
        }

        // ===== MFMA2 for position tile p2=p-1 (needs G cols 16p2..16p2+16) =====
        if (p >= 1) {
            const int p2 = p - 1;
            const int c0 = 16 * p2 + n;
            // q<48 -> G[t-1]=col c0 ; q>=48 -> G[t]=col c0+1
            bf16x8 B0 = *(const bf16x8*)(G + c0 * 96 + g * 16);
            bf16x8 B1 = *(const bf16x8*)(G + (c0 + (g >> 1)) * 96 +
                                         ((g < 2) ? (64 + g * 16) : ((g - 2) * 16)));
            bf16x8 B2 = *(const bf16x8*)(G + (c0 + 1) * 96 + 32 + g * 16);
            f32x4 h = {b1i0, b1i1, b1i2, b1i3};
            h = MFMA16(A2[0], B0, h);
            h = MFMA16(A2[1], B1, h);
            h = MFMA16(A2[2], B2, h);
            // rows j = g*4+reg ; j0..3 in g0 lanes, j4,j5 in g1 lanes regs 0,1
            float r20 = rcore(h.x), r21 = rcore(h.y), r22 = rcore(h.z), r23 = rcore(h.w);
            float u0 = __shfl(r20, n + 16, 64);
            float u1 = __shfl(r21, n + 16, 64);
            float y0 = b2s0 + w200 * r20 + w201 * r21 + w202 * r22 + w203 * r23
                            + w204 * u0 + w205 * u1;
            float y1 = b2s1 + w210 * r20 + w211 * r21 + w212 * r22 + w213 * r23
                            + w214 * u0 + w215 * u1;
            if (l < 16)
                reinterpret_cast<float2*>(out)[(size_t)b * TT + tb + 16 * p2 + n] =
                    make_float2(y0, y1);
        }
    }
}

extern "C" void kernel_launch(void* const* d_in, const int* in_sizes, int n_in,
                              void* d_out, int out_size, void* d_ws, size_t ws_size,
                              hipStream_t stream) {
    const float* x        = (const float*)d_in[0];
    const float* conv_w   = (const float*)d_in[1];
    const float* conv_b   = (const float*)d_in[2];
    const float* fc_hid_w = (const float*)d_in[3];
    const float* fc_hid_b = (const float*)d_in[4];
    const float* fc_out_w = (const float*)d_in[5];
    const float* fc_out_b = (const float*)d_in[6];
    float* out = (float*)d_out;
    unsigned int* wsu = (unsigned int*)d_ws;

    rvt_prep<<<1, 64, 0, stream>>>(conv_w, conv_b, fc_hid_w, fc_hid_b,
                                   fc_out_w, fc_out_b, wsu);

    const int grid = (BB * TT) / 256;   // 2048 blocks, 256 positions each
    rvt_mfma<<<grid, 256, 0, stream>>>(x, (const uint4*)d_ws,
                                       (const float*)d_ws + 2304, out);
}